// Round 3
// baseline (1631.082 us; speedup 1.0000x reference)
//
#include <hip/hip_runtime.h>
#include <hip/hip_bf16.h>

#define N_NODES 50000
#define E_EDGES 300000
#define IN_F 512
#define H_F 256
#define OUT_F 256
#define K_CL 4096
#define KW (K_CL / 32)
#define PCH 128

__device__ __forceinline__ unsigned fkey(float f) {
    unsigned u = __float_as_uint(f);
    return (u & 0x80000000u) ? ~u : (u | 0x80000000u);
}

// ---------------- init ----------------
__global__ __launch_bounds__(256) void init_nodes(int* cntD, int* degS,
                                                  unsigned long long* best_enc,
                                                  unsigned long long* bestpack, int* bgnode) {
    int i = blockIdx.x * blockDim.x + threadIdx.x;
    if (i < N_NODES) { cntD[i] = 0; degS[i] = 0; best_enc[i] = 0ULL; }
    if (i == 0) { *bestpack = 0ULL; *bgnode = 0x7FFFFFFF; }
}

__global__ __launch_bounds__(256) void deg_edges(const int* __restrict__ src,
                                                 const int* __restrict__ dst,
                                                 int* cntD, int* degS) {
    int e = blockIdx.x * blockDim.x + threadIdx.x;
    if (e >= E_EDGES) return;
    atomicAdd(&cntD[dst[e]], 1);
    atomicAdd(&degS[src[e]], 1);
}

__global__ __launch_bounds__(256) void make_dinv(const int* __restrict__ cntD, float* dinv) {
    int i = blockIdx.x * blockDim.x + threadIdx.x;
    if (i < N_NODES) dinv[i] = rsqrtf((float)cntD[i] + 1.0f);
}

// ---------------- fast fp32 GEMM: C = A(MxKd) @ B(KdxNc); Nc%128==0, Kd%16==0 ----------------
#define GBM 128
#define GBN 128
#define GBK 16
__global__ __launch_bounds__(256) void gemm_fast(const float* __restrict__ A,
                                                 const float* __restrict__ B,
                                                 float* __restrict__ C,
                                                 int M, int Nc, int Kd) {
    __shared__ float As[GBK][GBM];
    __shared__ float Bs[GBK][GBN];
    int tid = threadIdx.x;
    int tx = tid & 15, ty = tid >> 4;
    int row0 = blockIdx.y * GBM, col0 = blockIdx.x * GBN;
    float acc[2][2][4][4] = {};

    for (int k0 = 0; k0 < Kd; k0 += GBK) {
        #pragma unroll
        for (int half = 0; half < 2; ++half) {
            int f = tid + half * 256;
            int r = f >> 2, kq = f & 3;
            int gr = row0 + r;
            float4 v = {0.f, 0.f, 0.f, 0.f};
            if (gr < M) v = *(const float4*)&A[(long)gr * Kd + k0 + kq * 4];
            As[kq * 4 + 0][r] = v.x;
            As[kq * 4 + 1][r] = v.y;
            As[kq * 4 + 2][r] = v.z;
            As[kq * 4 + 3][r] = v.w;
        }
        #pragma unroll
        for (int half = 0; half < 2; ++half) {
            int f = tid + half * 256;
            int k = f >> 5, c4 = f & 31;
            float4 v = *(const float4*)&B[(long)(k0 + k) * Nc + col0 + c4 * 4];
            *(float4*)&Bs[k][c4 * 4] = v;
        }
        __syncthreads();
        #pragma unroll
        for (int k = 0; k < GBK; ++k) {
            float4 a0 = *(const float4*)&As[k][ty * 4];
            float4 a1 = *(const float4*)&As[k][ty * 4 + 64];
            float4 b0 = *(const float4*)&Bs[k][tx * 4];
            float4 b1 = *(const float4*)&Bs[k][tx * 4 + 64];
            float av[2][4] = {{a0.x, a0.y, a0.z, a0.w}, {a1.x, a1.y, a1.z, a1.w}};
            float bv[2][4] = {{b0.x, b0.y, b0.z, b0.w}, {b1.x, b1.y, b1.z, b1.w}};
            #pragma unroll
            for (int ri = 0; ri < 2; ++ri)
                #pragma unroll
                for (int ci = 0; ci < 2; ++ci)
                    #pragma unroll
                    for (int i = 0; i < 4; ++i)
                        #pragma unroll
                        for (int j = 0; j < 4; ++j)
                            acc[ri][ci][i][j] += av[ri][i] * bv[ci][j];
        }
        __syncthreads();
    }
    #pragma unroll
    for (int ri = 0; ri < 2; ++ri)
        #pragma unroll
        for (int i = 0; i < 4; ++i) {
            int gr = row0 + ri * 64 + ty * 4 + i;
            if (gr >= M) continue;
            #pragma unroll
            for (int ci = 0; ci < 2; ++ci) {
                float4 o = {acc[ri][ci][i][0], acc[ri][ci][i][1],
                            acc[ri][ci][i][2], acc[ri][ci][i][3]};
                *(float4*)&C[(long)gr * Nc + col0 + ci * 64 + tx * 4] = o;
            }
        }
}

// ---------------- generic single-block exclusive scan ----------------
__global__ __launch_bounds__(1024) void scan_generic(const int* __restrict__ cnt,
                                                     int* start, int* cur, int n) {
    __shared__ int s[1024];
    int tid = threadIdx.x;
    int CH = (n + 1023) / 1024;
    int lo = tid * CH;
    int hi = lo + CH; if (hi > n) hi = n;
    int sum = 0;
    for (int i = lo; i < hi; ++i) sum += cnt[i];
    s[tid] = sum;
    __syncthreads();
    for (int off = 1; off < 1024; off <<= 1) {
        int v = (tid >= off) ? s[tid - off] : 0;
        __syncthreads();
        s[tid] += v;
        __syncthreads();
    }
    int run = s[tid] - sum;
    for (int i = lo; i < hi; ++i) {
        start[i] = run; cur[i] = run; run += cnt[i];
    }
    if (tid == 1023) start[n] = s[1023];
}

__global__ __launch_bounds__(256) void csr_scatter(const int* __restrict__ src,
                                                   const int* __restrict__ dst,
                                                   int* cur, int* csr) {
    int e = blockIdx.x * blockDim.x + threadIdx.x;
    if (e >= E_EDGES) return;
    int d = dst[e];
    int p = atomicAdd(&cur[d], 1);
    csr[p] = src[e];
}

// ---------------- fused conv1 aggregation + relu + score ----------------
__global__ __launch_bounds__(256) void agg_fused(const float* __restrict__ h,
                                                 const float* __restrict__ dinv,
                                                 const int* __restrict__ rowptr,
                                                 const int* __restrict__ csr,
                                                 const float* __restrict__ b1,
                                                 const float* __restrict__ w_score,
                                                 float* x1, float* raw) {
    __shared__ int s_src[128];
    __shared__ float s_cf[128];
    __shared__ float red[256];
    int i = blockIdx.x, j = threadIdx.x;
    float di_ = dinv[i];
    float acc = di_ * di_ * h[(long)i * H_F + j];
    int p0 = rowptr[i], p1 = rowptr[i + 1];
    for (int base = p0; base < p1; base += 128) {
        int m = p1 - base; if (m > 128) m = 128;
        if (j < m) { int s = csr[base + j]; s_src[j] = s; s_cf[j] = dinv[s]; }
        __syncthreads();
        for (int t = 0; t < m; ++t)
            acc += (s_cf[t] * di_) * h[(long)s_src[t] * H_F + j];
        __syncthreads();
    }
    float v = fmaxf(acc + b1[j], 0.f);
    x1[(long)i * H_F + j] = v;
    red[j] = v * w_score[j];
    __syncthreads();
    for (int off = 128; off > 0; off >>= 1) {
        if (j < off) red[j] += red[j + off];
        __syncthreads();
    }
    if (j == 0) raw[i] = red[0];
}

// ---------------- top-K select (single block radix) ----------------
__global__ __launch_bounds__(1024) void topk_select(const float* __restrict__ raw,
                                                    unsigned* outT, int* outNeedEq) {
    __shared__ unsigned hist[256];
    __shared__ unsigned sh_prefix;
    __shared__ int sh_k;
    int tid = threadIdx.x;
    if (tid == 0) { sh_prefix = 0; sh_k = K_CL; }
    __syncthreads();
    for (int byte = 3; byte >= 0; --byte) {
        if (tid < 256) hist[tid] = 0;
        __syncthreads();
        unsigned prefix = sh_prefix;
        unsigned known_mask = (byte == 3) ? 0u : (0xFFFFFFFFu << ((byte + 1) * 8));
        for (int i = tid; i < N_NODES; i += 1024) {
            unsigned key = fkey(raw[i]);
            if ((key & known_mask) == prefix)
                atomicAdd(&hist[(key >> (byte * 8)) & 255], 1u);
        }
        __syncthreads();
        if (tid == 0) {
            int kk = sh_k;
            int cum = 0;
            int v = 255;
            for (; v > 0; --v) {
                int c = (int)hist[v];
                if (cum + c >= kk) break;
                cum += c;
            }
            sh_prefix = prefix | ((unsigned)v << (byte * 8));
            sh_k = kk - cum;
        }
        __syncthreads();
    }
    if (tid == 0) { *outT = sh_prefix; *outNeedEq = sh_k; }
}

// ---------------- deterministic ordered compaction ----------------
__global__ __launch_bounds__(1024) void topk_compact(const float* __restrict__ raw,
                                                     const unsigned* pT, const int* pNeedEq,
                                                     int* keep, int* cid) {
    __shared__ int s_gt[1024], s_eq[1024];
    int tid = threadIdx.x;
    unsigned T = *pT;
    int needEq = *pNeedEq;
    int chunk = (N_NODES + 1023) / 1024;
    int lo = tid * chunk;
    int hi = lo + chunk; if (hi > N_NODES) hi = N_NODES;
    int cgt = 0, ceq = 0;
    for (int i = lo; i < hi; ++i) {
        unsigned k = fkey(raw[i]);
        if (k > T) cgt++;
        else if (k == T) ceq++;
    }
    s_gt[tid] = cgt; s_eq[tid] = ceq;
    __syncthreads();
    for (int off = 1; off < 1024; off <<= 1) {
        int a = (tid >= off) ? s_gt[tid - off] : 0;
        int b = (tid >= off) ? s_eq[tid - off] : 0;
        __syncthreads();
        s_gt[tid] += a; s_eq[tid] += b;
        __syncthreads();
    }
    int totalGt = s_gt[1023];
    int g = s_gt[tid] - cgt;
    int e = s_eq[tid] - ceq;
    for (int i = lo; i < hi; ++i) {
        unsigned k = fkey(raw[i]);
        if (k > T) { keep[i] = 1; cid[i] = g; g++; }
        else if (k == T) {
            if (e < needEq) { keep[i] = 1; cid[i] = totalGt + e; }
            else { keep[i] = 0; cid[i] = -1; }
            e++;
        } else { keep[i] = 0; cid[i] = -1; }
    }
}

// ---------------- global fallback cluster ----------------
__global__ __launch_bounds__(256) void bg_pack(const int* __restrict__ keep,
                                               const int* __restrict__ degS,
                                               const float* __restrict__ raw,
                                               unsigned long long* bestpack) {
    int i = blockIdx.x * blockDim.x + threadIdx.x;
    if (i < N_NODES && keep[i]) {
        unsigned long long p = ((unsigned long long)(unsigned)degS[i] << 32) | fkey(raw[i]);
        atomicMax(bestpack, p);
    }
}

__global__ __launch_bounds__(256) void bg_node(const int* __restrict__ keep,
                                               const int* __restrict__ degS,
                                               const float* __restrict__ raw,
                                               const unsigned long long* bestpack, int* bgnode) {
    int i = blockIdx.x * blockDim.x + threadIdx.x;
    if (i < N_NODES && keep[i]) {
        unsigned long long p = ((unsigned long long)(unsigned)degS[i] << 32) | fkey(raw[i]);
        if (p == *bestpack) atomicMin(bgnode, i);
    }
}

// ---------------- neighbor attachment ----------------
__global__ __launch_bounds__(256) void neigh_edges(const int* __restrict__ src,
                                                   const int* __restrict__ dst,
                                                   const int* __restrict__ keep,
                                                   const int* __restrict__ degS,
                                                   unsigned long long* best_enc) {
    int e = blockIdx.x * blockDim.x + threadIdx.x;
    if (e >= 2 * E_EDGES) return;
    int s, t;
    if (e < E_EDGES) { s = src[e]; t = dst[e]; }
    else { s = dst[e - E_EDGES]; t = src[e - E_EDGES]; }
    if (!keep[s] && keep[t]) {
        unsigned long long enc =
            (unsigned long long)((long long)degS[t] * N_NODES + (N_NODES - 1 - t)) + 1ULL;
        atomicMax(&best_enc[s], enc);
    }
}

__global__ __launch_bounds__(256) void resolve_cid(const int* __restrict__ keep,
                                                   const unsigned long long* __restrict__ best_enc,
                                                   const int* __restrict__ bgnode, int* cid) {
    int i = blockIdx.x * blockDim.x + threadIdx.x;
    if (i >= N_NODES) return;
    if (keep[i]) return;
    unsigned long long v = best_enc[i];
    if (v > 0ULL) {
        long long enc = (long long)(v - 1ULL);
        int t = (N_NODES - 1) - (int)(enc % N_NODES);
        cid[i] = cid[t];
    } else {
        cid[i] = cid[*bgnode];
    }
}

// ---------------- cluster counting-sort ----------------
__global__ __launch_bounds__(256) void ccount(const int* __restrict__ cid, int* ccnt) {
    int i = blockIdx.x * blockDim.x + threadIdx.x;
    if (i < N_NODES) atomicAdd(&ccnt[cid[i]], 1);
}

__global__ __launch_bounds__(256) void cscatter(const int* __restrict__ cid, int* ccur, int* clist) {
    int i = blockIdx.x * blockDim.x + threadIdx.x;
    if (i >= N_NODES) return;
    int p = atomicAdd(&ccur[cid[i]], 1);
    clist[p] = i;
}

// ---------------- chunked segmented pooling (no hot atomics) ----------------
__global__ __launch_bounds__(256) void pool_chunk(const float* __restrict__ x1,
                                                  const float* __restrict__ raw,
                                                  const int* __restrict__ clist,
                                                  const int* __restrict__ cid,
                                                  float* xp) {
    __shared__ int s_node[PCH];
    __shared__ int s_c[PCH];
    __shared__ float s_g[PCH];
    int j = threadIdx.x;
    int base = blockIdx.x * PCH;
    int m = N_NODES - base; if (m > PCH) m = PCH;
    for (int t = j; t < m; t += 256) {
        int nd = clist[base + t];
        s_node[t] = nd;
        s_c[t] = cid[nd];
        s_g[t] = tanhf(raw[nd]);
    }
    __syncthreads();
    float acc = 0.f;
    int cprev = s_c[0];
    for (int t = 0; t < m; ++t) {
        int c = s_c[t];
        if (c != cprev) {
            atomicAdd(&xp[(long)cprev * H_F + j], acc);
            acc = 0.f;
            cprev = c;
        }
        acc += s_g[t] * x1[(long)s_node[t] * H_F + j];
    }
    atomicAdd(&xp[(long)cprev * H_F + j], acc);
}

__global__ __launch_bounds__(256) void pool_div(float* xp, const int* __restrict__ ccnt) {
    int i = blockIdx.x, j = threadIdx.x;
    float c = fmaxf((float)ccnt[i], 1.0f);
    xp[(long)i * H_F + j] /= c;
}

// ---------------- bit-packed pooled adjacency ----------------
__global__ __launch_bounds__(256) void build_Abits(const int* __restrict__ src,
                                                   const int* __restrict__ dst,
                                                   const int* __restrict__ cid,
                                                   unsigned* Abits) {
    int e = blockIdx.x * blockDim.x + threadIdx.x;
    if (e >= E_EDGES) return;
    int cu = cid[src[e]], cv = cid[dst[e]];
    if (cu != cv) atomicOr(&Abits[(long)cv * KW + (cu >> 5)], 1u << (cu & 31));
}

__global__ __launch_bounds__(256) void pop_di(const unsigned* __restrict__ Abits, float* di) {
    int i = blockIdx.x * blockDim.x + threadIdx.x;
    if (i >= K_CL) return;
    int c = 0;
    for (int w = 0; w < KW; ++w) c += __popc(Abits[(long)i * KW + w]);
    di[i] = rsqrtf((float)c + 1.0f);
}

__global__ __launch_bounds__(256) void scale_rows(const float* __restrict__ xpW2,
                                                  const float* __restrict__ di, float* Yp) {
    int i = blockIdx.x, j = threadIdx.x;
    Yp[(long)i * H_F + j] = di[i] * xpW2[(long)i * H_F + j];
}

// xp2[cv] = di[cv] * (sum_{A[cv][cu]=1} Yp[cu] + Yp[cv]) + b2
__global__ __launch_bounds__(256) void spmm_Z(const unsigned* __restrict__ Abits,
                                              const float* __restrict__ Yp,
                                              const float* __restrict__ di,
                                              const float* __restrict__ b2, float* xp2) {
    __shared__ unsigned s_row[KW];
    __shared__ float s_part[3][256];
    int cv = blockIdx.x;
    int tid = threadIdx.x;
    int w = tid >> 6, l = tid & 63;
    if (tid < KW) s_row[tid] = Abits[(long)cv * KW + tid];
    __syncthreads();
    float4 acc = {0.f, 0.f, 0.f, 0.f};
    const float4* Yp4 = (const float4*)Yp;
    for (int wi = w * (KW / 4); wi < (w + 1) * (KW / 4); ++wi) {
        unsigned word = s_row[wi];
        while (word) {
            int b = __ffs(word) - 1;
            word &= word - 1;
            int cu = wi * 32 + b;
            float4 y = Yp4[(long)cu * 64 + l];
            acc.x += y.x; acc.y += y.y; acc.z += y.z; acc.w += y.w;
        }
    }
    if (w > 0) *(float4*)&s_part[w - 1][l * 4] = acc;
    __syncthreads();
    if (w == 0) {
        #pragma unroll
        for (int ww = 0; ww < 3; ++ww) {
            float4 p = *(float4*)&s_part[ww][l * 4];
            acc.x += p.x; acc.y += p.y; acc.z += p.z; acc.w += p.w;
        }
        float dv = di[cv];
        float4 ys = Yp4[(long)cv * 64 + l];
        float4 o;
        o.x = dv * (acc.x + ys.x) + b2[l * 4 + 0];
        o.y = dv * (acc.y + ys.y) + b2[l * 4 + 1];
        o.z = dv * (acc.z + ys.z) + b2[l * 4 + 2];
        o.w = dv * (acc.w + ys.w) + b2[l * 4 + 3];
        *(float4*)&xp2[(long)cv * H_F + l * 4] = o;
    }
}

// ---------------- final add ----------------
__global__ __launch_bounds__(256) void final_add(float* out, const float* __restrict__ xp2,
                                                 const int* __restrict__ cid,
                                                 const float* __restrict__ b_skip) {
    int i = blockIdx.x, j = threadIdx.x;
    int c = cid[i];
    out[(long)i * OUT_F + j] += xp2[(long)c * OUT_F + j] + b_skip[j];
}

// ---------------- host launch ----------------
static inline size_t align256(size_t x) { return (x + 255) & ~(size_t)255; }

extern "C" void kernel_launch(void* const* d_in, const int* in_sizes, int n_in,
                              void* d_out, int out_size, void* d_ws, size_t ws_size,
                              hipStream_t stream) {
    const float* x      = (const float*)d_in[0];
    const int*   eidx   = (const int*)d_in[1];
    const float* W1     = (const float*)d_in[2];
    const float* b1     = (const float*)d_in[3];
    const float* W2     = (const float*)d_in[4];
    const float* b2     = (const float*)d_in[5];
    const float* wscore = (const float*)d_in[6];
    const float* Wskip  = (const float*)d_in[7];
    const float* bskip  = (const float*)d_in[8];
    float* out = (float*)d_out;

    const int* src = eidx;
    const int* dst = eidx + E_EDGES;

    char* ws = (char*)d_ws;
    size_t off = 0;
    auto alloc = [&](size_t bytes) { char* p = ws + off; off += align256(bytes); return p; };

    float* h     = (float*)alloc((size_t)N_NODES * H_F * 4);
    float* x1    = (float*)alloc((size_t)N_NODES * H_F * 4);
    float* raw   = (float*)alloc((size_t)N_NODES * 4);
    float* dinv  = (float*)alloc((size_t)N_NODES * 4);
    int*   cntD  = (int*)alloc((size_t)N_NODES * 4);
    int*   degS  = (int*)alloc((size_t)N_NODES * 4);
    int*   keep  = (int*)alloc((size_t)N_NODES * 4);
    int*   cid   = (int*)alloc((size_t)N_NODES * 4);
    unsigned long long* best_enc = (unsigned long long*)alloc((size_t)N_NODES * 8);
    int*   rowptr= (int*)alloc((size_t)(N_NODES + 1) * 4);
    int*   cur   = (int*)alloc((size_t)N_NODES * 4);
    int*   csr   = (int*)alloc((size_t)E_EDGES * 4);
    int*   ccnt  = (int*)alloc((size_t)K_CL * 4);
    int*   cstart= (int*)alloc((size_t)(K_CL + 1) * 4);
    int*   ccur  = (int*)alloc((size_t)K_CL * 4);
    int*   clist = (int*)alloc((size_t)N_NODES * 4);
    char*  small = alloc(64);
    unsigned* selT = (unsigned*)(small + 0);
    int* needEq    = (int*)(small + 4);
    unsigned long long* bestpack = (unsigned long long*)(small + 8);
    int* bgnode    = (int*)(small + 16);
    float* xp    = (float*)alloc((size_t)K_CL * H_F * 4);
    unsigned* Abits = (unsigned*)alloc((size_t)K_CL * KW * 4);
    float* di    = (float*)alloc((size_t)K_CL * 4);
    float* xpW2  = (float*)alloc((size_t)K_CL * H_F * 4);
    float* Yp    = (float*)alloc((size_t)K_CL * H_F * 4);
    float* xp2   = (float*)alloc((size_t)K_CL * H_F * 4);
    (void)ws_size; (void)n_in; (void)in_sizes; (void)out_size;

    int nb = (N_NODES + 255) / 256;
    int eb = (E_EDGES + 255) / 256;

    // degrees
    init_nodes<<<nb, 256, 0, stream>>>(cntD, degS, best_enc, bestpack, bgnode);
    deg_edges<<<eb, 256, 0, stream>>>(src, dst, cntD, degS);
    make_dinv<<<nb, 256, 0, stream>>>(cntD, dinv);

    // h = x @ W1
    {
        dim3 grid(H_F / GBN, (N_NODES + GBM - 1) / GBM);
        gemm_fast<<<grid, 256, 0, stream>>>(x, W1, h, N_NODES, H_F, IN_F);
    }

    // CSR by dst + fused aggregation
    scan_generic<<<1, 1024, 0, stream>>>(cntD, rowptr, cur, N_NODES);
    csr_scatter<<<eb, 256, 0, stream>>>(src, dst, cur, csr);
    agg_fused<<<N_NODES, 256, 0, stream>>>(h, dinv, rowptr, csr, b1, wscore, x1, raw);

    // top-K
    topk_select<<<1, 1024, 0, stream>>>(raw, selT, needEq);
    topk_compact<<<1, 1024, 0, stream>>>(raw, selT, needEq, keep, cid);

    // fallback cluster
    bg_pack<<<nb, 256, 0, stream>>>(keep, degS, raw, bestpack);
    bg_node<<<nb, 256, 0, stream>>>(keep, degS, raw, bestpack, bgnode);

    // neighbor attachment
    neigh_edges<<<(2 * E_EDGES + 255) / 256, 256, 0, stream>>>(src, dst, keep, degS, best_enc);
    resolve_cid<<<nb, 256, 0, stream>>>(keep, best_enc, bgnode, cid);

    // counting-sort nodes by cluster, then chunked segmented pooling
    hipMemsetAsync(ccnt, 0, (size_t)K_CL * 4, stream);
    ccount<<<nb, 256, 0, stream>>>(cid, ccnt);
    scan_generic<<<1, 1024, 0, stream>>>(ccnt, cstart, ccur, K_CL);
    cscatter<<<nb, 256, 0, stream>>>(cid, ccur, clist);
    hipMemsetAsync(xp, 0, (size_t)K_CL * H_F * 4, stream);
    pool_chunk<<<(N_NODES + PCH - 1) / PCH, 256, 0, stream>>>(x1, raw, clist, cid, xp);
    pool_div<<<K_CL, 256, 0, stream>>>(xp, ccnt);

    // xpW2 = xp @ W2
    {
        dim3 grid(H_F / GBN, K_CL / GBM);
        gemm_fast<<<grid, 256, 0, stream>>>(xp, W2, xpW2, K_CL, H_F, H_F);
    }

    // bit-packed pooled adjacency
    hipMemsetAsync(Abits, 0, (size_t)K_CL * KW * 4, stream);
    build_Abits<<<eb, 256, 0, stream>>>(src, dst, cid, Abits);
    pop_di<<<(K_CL + 255) / 256, 256, 0, stream>>>(Abits, di);
    scale_rows<<<K_CL, 256, 0, stream>>>(xpW2, di, Yp);
    spmm_Z<<<K_CL, 256, 0, stream>>>(Abits, Yp, di, b2, xp2);

    // skip connection GEMM straight into out
    {
        dim3 grid(OUT_F / GBN, (N_NODES + GBM - 1) / GBM);
        gemm_fast<<<grid, 256, 0, stream>>>(x1, Wskip, out, N_NODES, OUT_F, H_F);
    }
    final_add<<<N_NODES, 256, 0, stream>>>(out, xp2, cid, bskip);
}

// Round 4
// 1327.842 us; speedup vs baseline: 1.2284x; 1.2284x over previous
//
#include <hip/hip_runtime.h>
#include <hip/hip_bf16.h>

#define N_NODES 50000
#define E_EDGES 300000
#define IN_F 512
#define H_F 256
#define OUT_F 256
#define K_CL 4096
#define KW (K_CL / 32)
#define PCH 128

__device__ __forceinline__ unsigned fkey(float f) {
    unsigned u = __float_as_uint(f);
    return (u & 0x80000000u) ? ~u : (u | 0x80000000u);
}

// ---------------- init ----------------
__global__ __launch_bounds__(256) void init_nodes(int* cntD, int* degS,
                                                  unsigned long long* best_enc,
                                                  unsigned long long* bestpack, int* bgnode) {
    int i = blockIdx.x * blockDim.x + threadIdx.x;
    if (i < N_NODES) { cntD[i] = 0; degS[i] = 0; best_enc[i] = 0ULL; }
    if (i == 0) { *bestpack = 0ULL; *bgnode = 0x7FFFFFFF; }
}

__global__ __launch_bounds__(256) void deg_edges(const int* __restrict__ src,
                                                 const int* __restrict__ dst,
                                                 int* cntD, int* degS) {
    int e = blockIdx.x * blockDim.x + threadIdx.x;
    if (e >= E_EDGES) return;
    atomicAdd(&cntD[dst[e]], 1);
    atomicAdd(&degS[src[e]], 1);
}

__global__ __launch_bounds__(256) void make_dinv(const int* __restrict__ cntD, float* dinv) {
    int i = blockIdx.x * blockDim.x + threadIdx.x;
    if (i < N_NODES) dinv[i] = rsqrtf((float)cntD[i] + 1.0f);
}

// ---------------- pipelined fp32 GEMM: C = A(MxKd)@B(KdxNc); Nc%128==0, Kd%16==0 ----
// optional fused epilogue: C[r][c] = acc + xp2[cid[r]][c] + bskip[c]
#define GBM 128
#define GBN 128
#define GBK 16
__global__ __launch_bounds__(256) void gemm_pipe(const float* __restrict__ A,
                                                 const float* __restrict__ B,
                                                 float* __restrict__ C,
                                                 int M, int Nc, int Kd,
                                                 const int* __restrict__ cid,
                                                 const float* __restrict__ xp2,
                                                 const float* __restrict__ bskip) {
    __shared__ float As[GBK][GBM + 4];
    __shared__ float Bs[GBK][GBN];
    int tid = threadIdx.x;
    int tx = tid & 15, ty = tid >> 4;
    int row0 = blockIdx.y * GBM, col0 = blockIdx.x * GBN;
    float acc[2][2][4][4] = {};

    int ar[2], akq[2], bk[2], bc4[2];
    #pragma unroll
    for (int hf = 0; hf < 2; ++hf) {
        int f = tid + hf * 256;
        ar[hf] = f >> 2; akq[hf] = f & 3;
        bk[hf] = f >> 5; bc4[hf] = f & 31;
    }

    float4 ra[2], rb[2];

    auto load_tile = [&](int k0) {
        #pragma unroll
        for (int hf = 0; hf < 2; ++hf) {
            int gr = row0 + ar[hf];
            float4 v = {0.f, 0.f, 0.f, 0.f};
            if (gr < M) v = *(const float4*)&A[(long)gr * Kd + k0 + akq[hf] * 4];
            ra[hf] = v;
            rb[hf] = *(const float4*)&B[(long)(k0 + bk[hf]) * Nc + col0 + bc4[hf] * 4];
        }
    };
    auto store_tile = [&]() {
        #pragma unroll
        for (int hf = 0; hf < 2; ++hf) {
            As[akq[hf] * 4 + 0][ar[hf]] = ra[hf].x;
            As[akq[hf] * 4 + 1][ar[hf]] = ra[hf].y;
            As[akq[hf] * 4 + 2][ar[hf]] = ra[hf].z;
            As[akq[hf] * 4 + 3][ar[hf]] = ra[hf].w;
            *(float4*)&Bs[bk[hf]][bc4[hf] * 4] = rb[hf];
        }
    };
    auto compute = [&]() {
        #pragma unroll
        for (int k = 0; k < GBK; ++k) {
            float4 a0 = *(const float4*)&As[k][ty * 4];
            float4 a1 = *(const float4*)&As[k][ty * 4 + 64];
            float4 b0 = *(const float4*)&Bs[k][tx * 4];
            float4 b1 = *(const float4*)&Bs[k][tx * 4 + 64];
            float av[2][4] = {{a0.x, a0.y, a0.z, a0.w}, {a1.x, a1.y, a1.z, a1.w}};
            float bv[2][4] = {{b0.x, b0.y, b0.z, b0.w}, {b1.x, b1.y, b1.z, b1.w}};
            #pragma unroll
            for (int ri = 0; ri < 2; ++ri)
                #pragma unroll
                for (int ci = 0; ci < 2; ++ci)
                    #pragma unroll
                    for (int i = 0; i < 4; ++i)
                        #pragma unroll
                        for (int j = 0; j < 4; ++j)
                            acc[ri][ci][i][j] += av[ri][i] * bv[ci][j];
        }
    };

    load_tile(0);
    store_tile();
    __syncthreads();
    for (int k0 = GBK; k0 < Kd; k0 += GBK) {
        load_tile(k0);          // global loads in flight during compute
        compute();
        __syncthreads();
        store_tile();
        __syncthreads();
    }
    compute();

    #pragma unroll
    for (int ri = 0; ri < 2; ++ri)
        #pragma unroll
        for (int i = 0; i < 4; ++i) {
            int gr = row0 + ri * 64 + ty * 4 + i;
            if (gr >= M) continue;
            const float* xrow = cid ? (xp2 + (long)cid[gr] * H_F) : nullptr;
            #pragma unroll
            for (int ci = 0; ci < 2; ++ci) {
                int gc = col0 + ci * 64 + tx * 4;
                float4 o = {acc[ri][ci][i][0], acc[ri][ci][i][1],
                            acc[ri][ci][i][2], acc[ri][ci][i][3]};
                if (cid) {
                    float4 xr = *(const float4*)&xrow[gc];
                    float4 bs = *(const float4*)&bskip[gc];
                    o.x += xr.x + bs.x; o.y += xr.y + bs.y;
                    o.z += xr.z + bs.z; o.w += xr.w + bs.w;
                }
                *(float4*)&C[(long)gr * Nc + gc] = o;
            }
        }
}

// ---------------- generic single-block exclusive scan ----------------
__global__ __launch_bounds__(1024) void scan_generic(const int* __restrict__ cnt,
                                                     int* start, int* cur, int n) {
    __shared__ int s[1024];
    int tid = threadIdx.x;
    int CH = (n + 1023) / 1024;
    int lo = tid * CH;
    int hi = lo + CH; if (hi > n) hi = n;
    int sum = 0;
    for (int i = lo; i < hi; ++i) sum += cnt[i];
    s[tid] = sum;
    __syncthreads();
    for (int off = 1; off < 1024; off <<= 1) {
        int v = (tid >= off) ? s[tid - off] : 0;
        __syncthreads();
        s[tid] += v;
        __syncthreads();
    }
    int run = s[tid] - sum;
    for (int i = lo; i < hi; ++i) {
        start[i] = run; cur[i] = run; run += cnt[i];
    }
    if (tid == 1023) start[n] = s[1023];
}

__global__ __launch_bounds__(256) void csr_scatter(const int* __restrict__ src,
                                                   const int* __restrict__ dst,
                                                   int* cur, int* csr) {
    int e = blockIdx.x * blockDim.x + threadIdx.x;
    if (e >= E_EDGES) return;
    int d = dst[e];
    int p = atomicAdd(&cur[d], 1);
    csr[p] = src[e];
}

// ---------------- fused conv1 aggregation + relu + score ----------------
__global__ __launch_bounds__(256) void agg_fused(const float* __restrict__ h,
                                                 const float* __restrict__ dinv,
                                                 const int* __restrict__ rowptr,
                                                 const int* __restrict__ csr,
                                                 const float* __restrict__ b1,
                                                 const float* __restrict__ w_score,
                                                 float* x1, float* raw) {
    __shared__ int s_src[128];
    __shared__ float s_cf[128];
    __shared__ float red[256];
    int i = blockIdx.x, j = threadIdx.x;
    float di_ = dinv[i];
    float acc = di_ * di_ * h[(long)i * H_F + j];
    int p0 = rowptr[i], p1 = rowptr[i + 1];
    for (int base = p0; base < p1; base += 128) {
        int m = p1 - base; if (m > 128) m = 128;
        if (j < m) { int s = csr[base + j]; s_src[j] = s; s_cf[j] = dinv[s]; }
        __syncthreads();
        #pragma unroll 4
        for (int t = 0; t < m; ++t)
            acc += (s_cf[t] * di_) * h[(long)s_src[t] * H_F + j];
        __syncthreads();
    }
    float v = fmaxf(acc + b1[j], 0.f);
    x1[(long)i * H_F + j] = v;
    red[j] = v * w_score[j];
    __syncthreads();
    for (int off = 128; off > 0; off >>= 1) {
        if (j < off) red[j] += red[j + off];
        __syncthreads();
    }
    if (j == 0) raw[i] = red[0];
}

// ---------------- top-K select (single block radix) ----------------
__global__ __launch_bounds__(1024) void topk_select(const float* __restrict__ raw,
                                                    unsigned* outT, int* outNeedEq) {
    __shared__ unsigned hist[256];
    __shared__ unsigned sh_prefix;
    __shared__ int sh_k;
    int tid = threadIdx.x;
    if (tid == 0) { sh_prefix = 0; sh_k = K_CL; }
    __syncthreads();
    for (int byte = 3; byte >= 0; --byte) {
        if (tid < 256) hist[tid] = 0;
        __syncthreads();
        unsigned prefix = sh_prefix;
        unsigned known_mask = (byte == 3) ? 0u : (0xFFFFFFFFu << ((byte + 1) * 8));
        for (int i = tid; i < N_NODES; i += 1024) {
            unsigned key = fkey(raw[i]);
            if ((key & known_mask) == prefix)
                atomicAdd(&hist[(key >> (byte * 8)) & 255], 1u);
        }
        __syncthreads();
        if (tid == 0) {
            int kk = sh_k;
            int cum = 0;
            int v = 255;
            for (; v > 0; --v) {
                int c = (int)hist[v];
                if (cum + c >= kk) break;
                cum += c;
            }
            sh_prefix = prefix | ((unsigned)v << (byte * 8));
            sh_k = kk - cum;
        }
        __syncthreads();
    }
    if (tid == 0) { *outT = sh_prefix; *outNeedEq = sh_k; }
}

// ---------------- deterministic ordered compaction ----------------
__global__ __launch_bounds__(1024) void topk_compact(const float* __restrict__ raw,
                                                     const unsigned* pT, const int* pNeedEq,
                                                     int* keep, int* cid) {
    __shared__ int s_gt[1024], s_eq[1024];
    int tid = threadIdx.x;
    unsigned T = *pT;
    int needEq = *pNeedEq;
    int chunk = (N_NODES + 1023) / 1024;
    int lo = tid * chunk;
    int hi = lo + chunk; if (hi > N_NODES) hi = N_NODES;
    int cgt = 0, ceq = 0;
    for (int i = lo; i < hi; ++i) {
        unsigned k = fkey(raw[i]);
        if (k > T) cgt++;
        else if (k == T) ceq++;
    }
    s_gt[tid] = cgt; s_eq[tid] = ceq;
    __syncthreads();
    for (int off = 1; off < 1024; off <<= 1) {
        int a = (tid >= off) ? s_gt[tid - off] : 0;
        int b = (tid >= off) ? s_eq[tid - off] : 0;
        __syncthreads();
        s_gt[tid] += a; s_eq[tid] += b;
        __syncthreads();
    }
    int totalGt = s_gt[1023];
    int g = s_gt[tid] - cgt;
    int e = s_eq[tid] - ceq;
    for (int i = lo; i < hi; ++i) {
        unsigned k = fkey(raw[i]);
        if (k > T) { keep[i] = 1; cid[i] = g; g++; }
        else if (k == T) {
            if (e < needEq) { keep[i] = 1; cid[i] = totalGt + e; }
            else { keep[i] = 0; cid[i] = -1; }
            e++;
        } else { keep[i] = 0; cid[i] = -1; }
    }
}

// ---------------- global fallback cluster (wave-reduced atomics) ----------------
__global__ __launch_bounds__(256) void bg_pack(const int* __restrict__ keep,
                                               const int* __restrict__ degS,
                                               const float* __restrict__ raw,
                                               unsigned long long* bestpack) {
    int i = blockIdx.x * blockDim.x + threadIdx.x;
    unsigned long long p = 0ULL;
    if (i < N_NODES && keep[i])
        p = ((unsigned long long)(unsigned)degS[i] << 32) | fkey(raw[i]);
    #pragma unroll
    for (int o = 32; o > 0; o >>= 1) {
        unsigned long long q = __shfl_xor((long long)p, o, 64);
        if (q > p) p = q;
    }
    if ((threadIdx.x & 63) == 0 && p) atomicMax(bestpack, p);
}

__global__ __launch_bounds__(256) void bg_node(const int* __restrict__ keep,
                                               const int* __restrict__ degS,
                                               const float* __restrict__ raw,
                                               const unsigned long long* bestpack, int* bgnode) {
    int i = blockIdx.x * blockDim.x + threadIdx.x;
    if (i < N_NODES && keep[i]) {
        unsigned long long p = ((unsigned long long)(unsigned)degS[i] << 32) | fkey(raw[i]);
        if (p == *bestpack) atomicMin(bgnode, i);
    }
}

// ---------------- neighbor attachment ----------------
__global__ __launch_bounds__(256) void neigh_edges(const int* __restrict__ src,
                                                   const int* __restrict__ dst,
                                                   const int* __restrict__ keep,
                                                   const int* __restrict__ degS,
                                                   unsigned long long* best_enc) {
    int e = blockIdx.x * blockDim.x + threadIdx.x;
    if (e >= 2 * E_EDGES) return;
    int s, t;
    if (e < E_EDGES) { s = src[e]; t = dst[e]; }
    else { s = dst[e - E_EDGES]; t = src[e - E_EDGES]; }
    if (!keep[s] && keep[t]) {
        unsigned long long enc =
            (unsigned long long)((long long)degS[t] * N_NODES + (N_NODES - 1 - t)) + 1ULL;
        atomicMax(&best_enc[s], enc);
    }
}

__global__ __launch_bounds__(256) void resolve_cid(const int* __restrict__ keep,
                                                   const unsigned long long* __restrict__ best_enc,
                                                   const int* __restrict__ bgnode, int* cid) {
    int i = blockIdx.x * blockDim.x + threadIdx.x;
    if (i >= N_NODES) return;
    if (keep[i]) return;
    unsigned long long v = best_enc[i];
    if (v > 0ULL) {
        long long enc = (long long)(v - 1ULL);
        int t = (N_NODES - 1) - (int)(enc % N_NODES);
        cid[i] = cid[t];
    } else {
        cid[i] = cid[*bgnode];
    }
}

// ---------------- LDS-aggregated counting sort by cluster ----------------
#define NPB 1024
__global__ __launch_bounds__(256) void ccount2(const int* __restrict__ cid, int* ccnt) {
    __shared__ int hist[K_CL];
    for (int t = threadIdx.x; t < K_CL; t += 256) hist[t] = 0;
    __syncthreads();
    int base = blockIdx.x * NPB;
    #pragma unroll
    for (int u = 0; u < NPB / 256; ++u) {
        int idx = base + u * 256 + threadIdx.x;
        if (idx < N_NODES) atomicAdd(&hist[cid[idx]], 1);
    }
    __syncthreads();
    for (int t = threadIdx.x; t < K_CL; t += 256) {
        int hh = hist[t];
        if (hh) atomicAdd(&ccnt[t], hh);
    }
}

__global__ __launch_bounds__(256) void cscatter2(const int* __restrict__ cid,
                                                 int* ccur, int* clist) {
    __shared__ int hist[K_CL];
    for (int t = threadIdx.x; t < K_CL; t += 256) hist[t] = 0;
    __syncthreads();
    int base = blockIdx.x * NPB;
    int myc[NPB / 256], myr[NPB / 256];
    #pragma unroll
    for (int u = 0; u < NPB / 256; ++u) {
        int idx = base + u * 256 + threadIdx.x;
        if (idx < N_NODES) { myc[u] = cid[idx]; myr[u] = atomicAdd(&hist[myc[u]], 1); }
        else myc[u] = -1;
    }
    __syncthreads();
    for (int t = threadIdx.x; t < K_CL; t += 256) {
        int hh = hist[t];
        if (hh) hist[t] = atomicAdd(&ccur[t], hh);
    }
    __syncthreads();
    #pragma unroll
    for (int u = 0; u < NPB / 256; ++u)
        if (myc[u] >= 0) clist[hist[myc[u]] + myr[u]] = base + u * 256 + threadIdx.x;
}

// ---------------- chunked segmented pooling ----------------
__global__ __launch_bounds__(256) void pool_chunk(const float* __restrict__ x1,
                                                  const float* __restrict__ raw,
                                                  const int* __restrict__ clist,
                                                  const int* __restrict__ cid,
                                                  float* xp) {
    __shared__ int s_node[PCH];
    __shared__ int s_c[PCH];
    __shared__ float s_g[PCH];
    int j = threadIdx.x;
    int base = blockIdx.x * PCH;
    int m = N_NODES - base; if (m > PCH) m = PCH;
    for (int t = j; t < m; t += 256) {
        int nd = clist[base + t];
        s_node[t] = nd;
        s_c[t] = cid[nd];
        s_g[t] = tanhf(raw[nd]);
    }
    __syncthreads();
    float acc = 0.f;
    int cprev = s_c[0];
    for (int t = 0; t < m; t += 4) {
        int mm = m - t; if (mm > 4) mm = 4;
        float v[4];
        #pragma unroll
        for (int u = 0; u < 4; ++u)
            if (u < mm) v[u] = x1[(long)s_node[t + u] * H_F + j];
        #pragma unroll
        for (int u = 0; u < 4; ++u) {
            if (u < mm) {
                int c = s_c[t + u];
                if (c != cprev) {
                    atomicAdd(&xp[(long)cprev * H_F + j], acc);
                    acc = 0.f;
                    cprev = c;
                }
                acc += s_g[t + u] * v[u];
            }
        }
    }
    atomicAdd(&xp[(long)cprev * H_F + j], acc);
}

__global__ __launch_bounds__(256) void pool_div(float* xp, const int* __restrict__ ccnt) {
    int i = blockIdx.x, j = threadIdx.x;
    float c = fmaxf((float)ccnt[i], 1.0f);
    xp[(long)i * H_F + j] /= c;
}

// ---------------- bit-packed pooled adjacency ----------------
__global__ __launch_bounds__(256) void build_Abits(const int* __restrict__ src,
                                                   const int* __restrict__ dst,
                                                   const int* __restrict__ cid,
                                                   unsigned* Abits) {
    int e = blockIdx.x * blockDim.x + threadIdx.x;
    if (e >= E_EDGES) return;
    int cu = cid[src[e]], cv = cid[dst[e]];
    if (cu != cv) atomicOr(&Abits[(long)cv * KW + (cu >> 5)], 1u << (cu & 31));
}

__global__ __launch_bounds__(256) void pop_di(const unsigned* __restrict__ Abits, float* di) {
    int i = blockIdx.x * blockDim.x + threadIdx.x;
    if (i >= K_CL) return;
    int c = 0;
    for (int w = 0; w < KW; ++w) c += __popc(Abits[(long)i * KW + w]);
    di[i] = rsqrtf((float)c + 1.0f);
}

// xp2[cv] = di[cv]*( sum_{A[cv][cu]=1} di[cu]*xpW2[cu] + di[cv]*xpW2[cv] ) + b2
__global__ __launch_bounds__(256) void spmm_Z(const unsigned* __restrict__ Abits,
                                              const float* __restrict__ xpW2,
                                              const float* __restrict__ di,
                                              const float* __restrict__ b2, float* xp2) {
    __shared__ unsigned s_row[KW];
    __shared__ float s_part[3][256];
    int cv = blockIdx.x;
    int tid = threadIdx.x;
    int w = tid >> 6, l = tid & 63;
    if (tid < KW) s_row[tid] = Abits[(long)cv * KW + tid];
    __syncthreads();
    float4 acc = {0.f, 0.f, 0.f, 0.f};
    const float4* Y4 = (const float4*)xpW2;
    for (int wi = w * (KW / 4); wi < (w + 1) * (KW / 4); ++wi) {
        unsigned word = s_row[wi];
        while (word) {
            int b = __ffs(word) - 1;
            word &= word - 1;
            int cu = wi * 32 + b;
            float dcu = di[cu];
            float4 y = Y4[(long)cu * 64 + l];
            acc.x += dcu * y.x; acc.y += dcu * y.y;
            acc.z += dcu * y.z; acc.w += dcu * y.w;
        }
    }
    if (w > 0) *(float4*)&s_part[w - 1][l * 4] = acc;
    __syncthreads();
    if (w == 0) {
        #pragma unroll
        for (int ww = 0; ww < 3; ++ww) {
            float4 p = *(float4*)&s_part[ww][l * 4];
            acc.x += p.x; acc.y += p.y; acc.z += p.z; acc.w += p.w;
        }
        float dv = di[cv];
        float4 ys = Y4[(long)cv * 64 + l];
        float4 o;
        o.x = dv * (acc.x + dv * ys.x) + b2[l * 4 + 0];
        o.y = dv * (acc.y + dv * ys.y) + b2[l * 4 + 1];
        o.z = dv * (acc.z + dv * ys.z) + b2[l * 4 + 2];
        o.w = dv * (acc.w + dv * ys.w) + b2[l * 4 + 3];
        *(float4*)&xp2[(long)cv * H_F + l * 4] = o;
    }
}

// ---------------- host launch ----------------
static inline size_t align256(size_t x) { return (x + 255) & ~(size_t)255; }

extern "C" void kernel_launch(void* const* d_in, const int* in_sizes, int n_in,
                              void* d_out, int out_size, void* d_ws, size_t ws_size,
                              hipStream_t stream) {
    const float* x      = (const float*)d_in[0];
    const int*   eidx   = (const int*)d_in[1];
    const float* W1     = (const float*)d_in[2];
    const float* b1     = (const float*)d_in[3];
    const float* W2     = (const float*)d_in[4];
    const float* b2     = (const float*)d_in[5];
    const float* wscore = (const float*)d_in[6];
    const float* Wskip  = (const float*)d_in[7];
    const float* bskip  = (const float*)d_in[8];
    float* out = (float*)d_out;

    const int* src = eidx;
    const int* dst = eidx + E_EDGES;

    char* ws = (char*)d_ws;
    size_t off = 0;
    auto alloc = [&](size_t bytes) { char* p = ws + off; off += align256(bytes); return p; };

    float* h     = (float*)alloc((size_t)N_NODES * H_F * 4);
    float* x1    = (float*)alloc((size_t)N_NODES * H_F * 4);
    float* raw   = (float*)alloc((size_t)N_NODES * 4);
    float* dinv  = (float*)alloc((size_t)N_NODES * 4);
    int*   cntD  = (int*)alloc((size_t)N_NODES * 4);
    int*   degS  = (int*)alloc((size_t)N_NODES * 4);
    int*   keep  = (int*)alloc((size_t)N_NODES * 4);
    int*   cid   = (int*)alloc((size_t)N_NODES * 4);
    unsigned long long* best_enc = (unsigned long long*)alloc((size_t)N_NODES * 8);
    int*   rowptr= (int*)alloc((size_t)(N_NODES + 1) * 4);
    int*   cur   = (int*)alloc((size_t)N_NODES * 4);
    int*   csr   = (int*)alloc((size_t)E_EDGES * 4);
    int*   ccnt  = (int*)alloc((size_t)K_CL * 4);
    int*   cstart= (int*)alloc((size_t)(K_CL + 1) * 4);
    int*   ccur  = (int*)alloc((size_t)K_CL * 4);
    int*   clist = (int*)alloc((size_t)N_NODES * 4);
    char*  small = alloc(64);
    unsigned* selT = (unsigned*)(small + 0);
    int* needEq    = (int*)(small + 4);
    unsigned long long* bestpack = (unsigned long long*)(small + 8);
    int* bgnode    = (int*)(small + 16);
    float* xp    = (float*)alloc((size_t)K_CL * H_F * 4);
    unsigned* Abits = (unsigned*)alloc((size_t)K_CL * KW * 4);
    float* di    = (float*)alloc((size_t)K_CL * 4);
    float* xpW2  = (float*)alloc((size_t)K_CL * H_F * 4);
    float* xp2   = (float*)alloc((size_t)K_CL * H_F * 4);
    (void)ws_size; (void)n_in; (void)in_sizes; (void)out_size;

    int nb = (N_NODES + 255) / 256;
    int eb = (E_EDGES + 255) / 256;

    // degrees
    init_nodes<<<nb, 256, 0, stream>>>(cntD, degS, best_enc, bestpack, bgnode);
    deg_edges<<<eb, 256, 0, stream>>>(src, dst, cntD, degS);
    make_dinv<<<nb, 256, 0, stream>>>(cntD, dinv);

    // h = x @ W1
    {
        dim3 grid(H_F / GBN, (N_NODES + GBM - 1) / GBM);
        gemm_pipe<<<grid, 256, 0, stream>>>(x, W1, h, N_NODES, H_F, IN_F,
                                            nullptr, nullptr, nullptr);
    }

    // CSR by dst + fused aggregation
    scan_generic<<<1, 1024, 0, stream>>>(cntD, rowptr, cur, N_NODES);
    csr_scatter<<<eb, 256, 0, stream>>>(src, dst, cur, csr);
    agg_fused<<<N_NODES, 256, 0, stream>>>(h, dinv, rowptr, csr, b1, wscore, x1, raw);

    // top-K
    topk_select<<<1, 1024, 0, stream>>>(raw, selT, needEq);
    topk_compact<<<1, 1024, 0, stream>>>(raw, selT, needEq, keep, cid);

    // fallback cluster
    bg_pack<<<nb, 256, 0, stream>>>(keep, degS, raw, bestpack);
    bg_node<<<nb, 256, 0, stream>>>(keep, degS, raw, bestpack, bgnode);

    // neighbor attachment
    neigh_edges<<<(2 * E_EDGES + 255) / 256, 256, 0, stream>>>(src, dst, keep, degS, best_enc);
    resolve_cid<<<nb, 256, 0, stream>>>(keep, best_enc, bgnode, cid);

    // LDS-aggregated counting sort by cluster, then chunked segmented pooling
    hipMemsetAsync(ccnt, 0, (size_t)K_CL * 4, stream);
    {
        int cb = (N_NODES + NPB - 1) / NPB;
        ccount2<<<cb, 256, 0, stream>>>(cid, ccnt);
        scan_generic<<<1, 1024, 0, stream>>>(ccnt, cstart, ccur, K_CL);
        cscatter2<<<cb, 256, 0, stream>>>(cid, ccur, clist);
    }
    hipMemsetAsync(xp, 0, (size_t)K_CL * H_F * 4, stream);
    pool_chunk<<<(N_NODES + PCH - 1) / PCH, 256, 0, stream>>>(x1, raw, clist, cid, xp);
    pool_div<<<K_CL, 256, 0, stream>>>(xp, ccnt);

    // xpW2 = xp @ W2
    {
        dim3 grid(H_F / GBN, K_CL / GBM);
        gemm_pipe<<<grid, 256, 0, stream>>>(xp, W2, xpW2, K_CL, H_F, H_F,
                                            nullptr, nullptr, nullptr);
    }

    // bit-packed pooled adjacency + normalized SpMM (di folded in)
    hipMemsetAsync(Abits, 0, (size_t)K_CL * KW * 4, stream);
    build_Abits<<<eb, 256, 0, stream>>>(src, dst, cid, Abits);
    pop_di<<<(K_CL + 255) / 256, 256, 0, stream>>>(Abits, di);
    spmm_Z<<<K_CL, 256, 0, stream>>>(Abits, xpW2, di, b2, xp2);

    // skip GEMM with fused broadcast epilogue: out = x1@Wskip + xp2[cid] + b_skip
    {
        dim3 grid(OUT_F / GBN, (N_NODES + GBM - 1) / GBM);
        gemm_pipe<<<grid, 256, 0, stream>>>(x1, Wskip, out, N_NODES, OUT_F, H_F,
                                            cid, xp2, bskip);
    }
}

// Round 5
// 1195.941 us; speedup vs baseline: 1.3638x; 1.1103x over previous
//
#include <hip/hip_runtime.h>
#include <hip/hip_bf16.h>

#define N_NODES 50000
#define E_EDGES 300000
#define IN_F 512
#define H_F 256
#define OUT_F 256
#define K_CL 4096
#define KW (K_CL / 32)
#define PCH 128

__device__ __forceinline__ unsigned fkey(float f) {
    unsigned u = __float_as_uint(f);
    return (u & 0x80000000u) ? ~u : (u | 0x80000000u);
}

// ---------------- init ----------------
__global__ __launch_bounds__(256) void init_nodes(int* cntD, int* degS,
                                                  unsigned long long* best_enc,
                                                  unsigned long long* bestpack, int* bgnode) {
    int i = blockIdx.x * blockDim.x + threadIdx.x;
    if (i < N_NODES) { cntD[i] = 0; degS[i] = 0; best_enc[i] = 0ULL; }
    if (i == 0) { *bestpack = 0ULL; *bgnode = 0x7FFFFFFF; }
}

__global__ __launch_bounds__(256) void deg_edges(const int* __restrict__ src,
                                                 const int* __restrict__ dst,
                                                 int* cntD, int* degS) {
    int e = blockIdx.x * blockDim.x + threadIdx.x;
    if (e >= E_EDGES) return;
    atomicAdd(&cntD[dst[e]], 1);
    atomicAdd(&degS[src[e]], 1);
}

__global__ __launch_bounds__(256) void make_dinv(const int* __restrict__ cntD, float* dinv) {
    int i = blockIdx.x * blockDim.x + threadIdx.x;
    if (i < N_NODES) dinv[i] = rsqrtf((float)cntD[i] + 1.0f);
}

// ---- double-buffered fp32 GEMM, B staged via global_load_lds, A reg-transient ----
// C = A(MxKd) @ B(KdxNc); Nc%128==0, Kd%16==0.
// optional fused epilogue: C[r][c] = acc + xp2[cid[r]][c] + bskip[c]
#define GBM 128
#define GBN 128
#define GBK 16
#define APAD 4
__global__ __launch_bounds__(256) void gemm_db(const float* __restrict__ A,
                                               const float* __restrict__ B,
                                               float* __restrict__ C,
                                               int M, int Nc, int Kd,
                                               const int* __restrict__ cid,
                                               const float* __restrict__ xp2,
                                               const float* __restrict__ bskip) {
    __shared__ float As[2][GBK][GBM + APAD];
    __shared__ float Bs[2][GBK][GBN];
    int tid = threadIdx.x;
    int tx = tid & 15, ty = tid >> 4;
    int lane = tid & 63;
    int wave = tid >> 6;
    int row0 = blockIdx.y * GBM, col0 = blockIdx.x * GBN;
    float acc[2][2][4][4] = {};

    int ar[2], akq[2];
    #pragma unroll
    for (int hf = 0; hf < 2; ++hf) {
        int f = tid + hf * 256;
        ar[hf] = f >> 2; akq[hf] = f & 3;
    }

    // stage B tile rows [k0, k0+16) into Bs[bb] via async global->LDS (no VGPRs).
    // chunk = wave*2+u covers 2 rows (1 KB): lane l -> row chunk*2 + (l>>5), word (l&31)*4.
    auto stage_B = [&](int k0, int bb) {
        #pragma unroll
        for (int u = 0; u < 2; ++u) {
            int chunk = wave * 2 + u;
            int krow = chunk * 2 + (lane >> 5);
            const float* gsrc = &B[(long)(k0 + krow) * Nc + col0 + (lane & 31) * 4];
            __builtin_amdgcn_global_load_lds(
                (const __attribute__((address_space(1))) void*)gsrc,
                (__attribute__((address_space(3))) void*)&Bs[bb][chunk * 2][0],
                16, 0, 0);
        }
    };
    // stage A tile (transposed store) through transient registers
    auto stage_A = [&](int k0, int bb) {
        #pragma unroll
        for (int hf = 0; hf < 2; ++hf) {
            int gr = row0 + ar[hf];
            float4 v = {0.f, 0.f, 0.f, 0.f};
            if (gr < M) v = *(const float4*)&A[(long)gr * Kd + k0 + akq[hf] * 4];
            As[bb][akq[hf] * 4 + 0][ar[hf]] = v.x;
            As[bb][akq[hf] * 4 + 1][ar[hf]] = v.y;
            As[bb][akq[hf] * 4 + 2][ar[hf]] = v.z;
            As[bb][akq[hf] * 4 + 3][ar[hf]] = v.w;
        }
    };
    auto compute = [&](int bb) {
        #pragma unroll
        for (int k = 0; k < GBK; ++k) {
            float4 a0 = *(const float4*)&As[bb][k][ty * 4];
            float4 a1 = *(const float4*)&As[bb][k][ty * 4 + 64];
            float4 b0 = *(const float4*)&Bs[bb][k][tx * 4];
            float4 b1 = *(const float4*)&Bs[bb][k][tx * 4 + 64];
            float av[2][4] = {{a0.x, a0.y, a0.z, a0.w}, {a1.x, a1.y, a1.z, a1.w}};
            float bv[2][4] = {{b0.x, b0.y, b0.z, b0.w}, {b1.x, b1.y, b1.z, b1.w}};
            #pragma unroll
            for (int ri = 0; ri < 2; ++ri)
                #pragma unroll
                for (int ci = 0; ci < 2; ++ci)
                    #pragma unroll
                    for (int i = 0; i < 4; ++i)
                        #pragma unroll
                        for (int j = 0; j < 4; ++j)
                            acc[ri][ci][i][j] += av[ri][i] * bv[ci][j];
        }
    };

    stage_B(0, 0);
    stage_A(0, 0);
    __syncthreads();
    int nt = Kd / GBK;
    for (int t = 0; t < nt; ++t) {
        int cb = t & 1;
        if (t + 1 < nt) {
            stage_B(GBK * (t + 1), cb ^ 1);   // async, lands before next barrier
            stage_A(GBK * (t + 1), cb ^ 1);   // transient regs
        }
        compute(cb);
        __syncthreads();
    }

    #pragma unroll
    for (int ri = 0; ri < 2; ++ri)
        #pragma unroll
        for (int i = 0; i < 4; ++i) {
            int gr = row0 + ri * 64 + ty * 4 + i;
            if (gr >= M) continue;
            const float* xrow = cid ? (xp2 + (long)cid[gr] * H_F) : nullptr;
            #pragma unroll
            for (int ci = 0; ci < 2; ++ci) {
                int gc = col0 + ci * 64 + tx * 4;
                float4 o = {acc[ri][ci][i][0], acc[ri][ci][i][1],
                            acc[ri][ci][i][2], acc[ri][ci][i][3]};
                if (cid) {
                    float4 xr = *(const float4*)&xrow[gc];
                    float4 bs = *(const float4*)&bskip[gc];
                    o.x += xr.x + bs.x; o.y += xr.y + bs.y;
                    o.z += xr.z + bs.z; o.w += xr.w + bs.w;
                }
                *(float4*)&C[(long)gr * Nc + gc] = o;
            }
        }
}

// ---------------- generic single-block exclusive scan ----------------
__global__ __launch_bounds__(1024) void scan_generic(const int* __restrict__ cnt,
                                                     int* start, int* cur, int n) {
    __shared__ int s[1024];
    int tid = threadIdx.x;
    int CH = (n + 1023) / 1024;
    int lo = tid * CH;
    int hi = lo + CH; if (hi > n) hi = n;
    int sum = 0;
    for (int i = lo; i < hi; ++i) sum += cnt[i];
    s[tid] = sum;
    __syncthreads();
    for (int off = 1; off < 1024; off <<= 1) {
        int v = (tid >= off) ? s[tid - off] : 0;
        __syncthreads();
        s[tid] += v;
        __syncthreads();
    }
    int run = s[tid] - sum;
    for (int i = lo; i < hi; ++i) {
        start[i] = run; cur[i] = run; run += cnt[i];
    }
    if (tid == 1023) start[n] = s[1023];
}

__global__ __launch_bounds__(256) void csr_scatter(const int* __restrict__ src,
                                                   const int* __restrict__ dst,
                                                   int* cur, int* csr) {
    int e = blockIdx.x * blockDim.x + threadIdx.x;
    if (e >= E_EDGES) return;
    int d = dst[e];
    int p = atomicAdd(&cur[d], 1);
    csr[p] = src[e];
}

// ---------------- fused conv1 aggregation + relu + score ----------------
__global__ __launch_bounds__(256) void agg_fused(const float* __restrict__ h,
                                                 const float* __restrict__ dinv,
                                                 const int* __restrict__ rowptr,
                                                 const int* __restrict__ csr,
                                                 const float* __restrict__ b1,
                                                 const float* __restrict__ w_score,
                                                 float* x1, float* raw) {
    __shared__ int s_src[128];
    __shared__ float s_cf[128];
    __shared__ float red[256];
    int i = blockIdx.x, j = threadIdx.x;
    float di_ = dinv[i];
    float acc = di_ * di_ * h[(long)i * H_F + j];
    int p0 = rowptr[i], p1 = rowptr[i + 1];
    for (int base = p0; base < p1; base += 128) {
        int m = p1 - base; if (m > 128) m = 128;
        if (j < m) { int s = csr[base + j]; s_src[j] = s; s_cf[j] = dinv[s]; }
        __syncthreads();
        #pragma unroll 4
        for (int t = 0; t < m; ++t)
            acc += (s_cf[t] * di_) * h[(long)s_src[t] * H_F + j];
        __syncthreads();
    }
    float v = fmaxf(acc + b1[j], 0.f);
    x1[(long)i * H_F + j] = v;
    red[j] = v * w_score[j];
    __syncthreads();
    for (int off = 128; off > 0; off >>= 1) {
        if (j < off) red[j] += red[j + off];
        __syncthreads();
    }
    if (j == 0) raw[i] = red[0];
}

// ---------------- top-K select (single block radix) ----------------
__global__ __launch_bounds__(1024) void topk_select(const float* __restrict__ raw,
                                                    unsigned* outT, int* outNeedEq) {
    __shared__ unsigned hist[256];
    __shared__ unsigned sh_prefix;
    __shared__ int sh_k;
    int tid = threadIdx.x;
    if (tid == 0) { sh_prefix = 0; sh_k = K_CL; }
    __syncthreads();
    for (int byte = 3; byte >= 0; --byte) {
        if (tid < 256) hist[tid] = 0;
        __syncthreads();
        unsigned prefix = sh_prefix;
        unsigned known_mask = (byte == 3) ? 0u : (0xFFFFFFFFu << ((byte + 1) * 8));
        for (int i = tid; i < N_NODES; i += 1024) {
            unsigned key = fkey(raw[i]);
            if ((key & known_mask) == prefix)
                atomicAdd(&hist[(key >> (byte * 8)) & 255], 1u);
        }
        __syncthreads();
        if (tid == 0) {
            int kk = sh_k;
            int cum = 0;
            int v = 255;
            for (; v > 0; --v) {
                int c = (int)hist[v];
                if (cum + c >= kk) break;
                cum += c;
            }
            sh_prefix = prefix | ((unsigned)v << (byte * 8));
            sh_k = kk - cum;
        }
        __syncthreads();
    }
    if (tid == 0) { *outT = sh_prefix; *outNeedEq = sh_k; }
}

// ---------------- deterministic ordered compaction ----------------
__global__ __launch_bounds__(1024) void topk_compact(const float* __restrict__ raw,
                                                     const unsigned* pT, const int* pNeedEq,
                                                     int* keep, int* cid) {
    __shared__ int s_gt[1024], s_eq[1024];
    int tid = threadIdx.x;
    unsigned T = *pT;
    int needEq = *pNeedEq;
    int chunk = (N_NODES + 1023) / 1024;
    int lo = tid * chunk;
    int hi = lo + chunk; if (hi > N_NODES) hi = N_NODES;
    int cgt = 0, ceq = 0;
    for (int i = lo; i < hi; ++i) {
        unsigned k = fkey(raw[i]);
        if (k > T) cgt++;
        else if (k == T) ceq++;
    }
    s_gt[tid] = cgt; s_eq[tid] = ceq;
    __syncthreads();
    for (int off = 1; off < 1024; off <<= 1) {
        int a = (tid >= off) ? s_gt[tid - off] : 0;
        int b = (tid >= off) ? s_eq[tid - off] : 0;
        __syncthreads();
        s_gt[tid] += a; s_eq[tid] += b;
        __syncthreads();
    }
    int totalGt = s_gt[1023];
    int g = s_gt[tid] - cgt;
    int e = s_eq[tid] - ceq;
    for (int i = lo; i < hi; ++i) {
        unsigned k = fkey(raw[i]);
        if (k > T) { keep[i] = 1; cid[i] = g; g++; }
        else if (k == T) {
            if (e < needEq) { keep[i] = 1; cid[i] = totalGt + e; }
            else { keep[i] = 0; cid[i] = -1; }
            e++;
        } else { keep[i] = 0; cid[i] = -1; }
    }
}

// ---------------- global fallback cluster (wave-reduced atomics) ----------------
__global__ __launch_bounds__(256) void bg_pack(const int* __restrict__ keep,
                                               const int* __restrict__ degS,
                                               const float* __restrict__ raw,
                                               unsigned long long* bestpack) {
    int i = blockIdx.x * blockDim.x + threadIdx.x;
    unsigned long long p = 0ULL;
    if (i < N_NODES && keep[i])
        p = ((unsigned long long)(unsigned)degS[i] << 32) | fkey(raw[i]);
    #pragma unroll
    for (int o = 32; o > 0; o >>= 1) {
        unsigned long long q = __shfl_xor((long long)p, o, 64);
        if (q > p) p = q;
    }
    if ((threadIdx.x & 63) == 0 && p) atomicMax(bestpack, p);
}

__global__ __launch_bounds__(256) void bg_node(const int* __restrict__ keep,
                                               const int* __restrict__ degS,
                                               const float* __restrict__ raw,
                                               const unsigned long long* bestpack, int* bgnode) {
    int i = blockIdx.x * blockDim.x + threadIdx.x;
    if (i < N_NODES && keep[i]) {
        unsigned long long p = ((unsigned long long)(unsigned)degS[i] << 32) | fkey(raw[i]);
        if (p == *bestpack) atomicMin(bgnode, i);
    }
}

// ---------------- neighbor attachment ----------------
__global__ __launch_bounds__(256) void neigh_edges(const int* __restrict__ src,
                                                   const int* __restrict__ dst,
                                                   const int* __restrict__ keep,
                                                   const int* __restrict__ degS,
                                                   unsigned long long* best_enc) {
    int e = blockIdx.x * blockDim.x + threadIdx.x;
    if (e >= 2 * E_EDGES) return;
    int s, t;
    if (e < E_EDGES) { s = src[e]; t = dst[e]; }
    else { s = dst[e - E_EDGES]; t = src[e - E_EDGES]; }
    if (!keep[s] && keep[t]) {
        unsigned long long enc =
            (unsigned long long)((long long)degS[t] * N_NODES + (N_NODES - 1 - t)) + 1ULL;
        atomicMax(&best_enc[s], enc);
    }
}

__global__ __launch_bounds__(256) void resolve_cid(const int* __restrict__ keep,
                                                   const unsigned long long* __restrict__ best_enc,
                                                   const int* __restrict__ bgnode, int* cid) {
    int i = blockIdx.x * blockDim.x + threadIdx.x;
    if (i >= N_NODES) return;
    if (keep[i]) return;
    unsigned long long v = best_enc[i];
    if (v > 0ULL) {
        long long enc = (long long)(v - 1ULL);
        int t = (N_NODES - 1) - (int)(enc % N_NODES);
        cid[i] = cid[t];
    } else {
        cid[i] = cid[*bgnode];
    }
}

// ---------------- LDS-aggregated counting sort by cluster ----------------
#define NPB 1024
__global__ __launch_bounds__(256) void ccount2(const int* __restrict__ cid, int* ccnt) {
    __shared__ int hist[K_CL];
    for (int t = threadIdx.x; t < K_CL; t += 256) hist[t] = 0;
    __syncthreads();
    int base = blockIdx.x * NPB;
    #pragma unroll
    for (int u = 0; u < NPB / 256; ++u) {
        int idx = base + u * 256 + threadIdx.x;
        if (idx < N_NODES) atomicAdd(&hist[cid[idx]], 1);
    }
    __syncthreads();
    for (int t = threadIdx.x; t < K_CL; t += 256) {
        int hh = hist[t];
        if (hh) atomicAdd(&ccnt[t], hh);
    }
}

__global__ __launch_bounds__(256) void cscatter2(const int* __restrict__ cid,
                                                 int* ccur, int* clist) {
    __shared__ int hist[K_CL];
    for (int t = threadIdx.x; t < K_CL; t += 256) hist[t] = 0;
    __syncthreads();
    int base = blockIdx.x * NPB;
    int myc[NPB / 256], myr[NPB / 256];
    #pragma unroll
    for (int u = 0; u < NPB / 256; ++u) {
        int idx = base + u * 256 + threadIdx.x;
        if (idx < N_NODES) { myc[u] = cid[idx]; myr[u] = atomicAdd(&hist[myc[u]], 1); }
        else myc[u] = -1;
    }
    __syncthreads();
    for (int t = threadIdx.x; t < K_CL; t += 256) {
        int hh = hist[t];
        if (hh) hist[t] = atomicAdd(&ccur[t], hh);
    }
    __syncthreads();
    #pragma unroll
    for (int u = 0; u < NPB / 256; ++u)
        if (myc[u] >= 0) clist[hist[myc[u]] + myr[u]] = base + u * 256 + threadIdx.x;
}

// ---------------- chunked segmented pooling ----------------
__global__ __launch_bounds__(256) void pool_chunk(const float* __restrict__ x1,
                                                  const float* __restrict__ raw,
                                                  const int* __restrict__ clist,
                                                  const int* __restrict__ cid,
                                                  float* xp) {
    __shared__ int s_node[PCH];
    __shared__ int s_c[PCH];
    __shared__ float s_g[PCH];
    int j = threadIdx.x;
    int base = blockIdx.x * PCH;
    int m = N_NODES - base; if (m > PCH) m = PCH;
    for (int t = j; t < m; t += 256) {
        int nd = clist[base + t];
        s_node[t] = nd;
        s_c[t] = cid[nd];
        s_g[t] = tanhf(raw[nd]);
    }
    __syncthreads();
    float acc = 0.f;
    int cprev = s_c[0];
    for (int t = 0; t < m; t += 4) {
        int mm = m - t; if (mm > 4) mm = 4;
        float v[4];
        #pragma unroll
        for (int u = 0; u < 4; ++u)
            if (u < mm) v[u] = x1[(long)s_node[t + u] * H_F + j];
        #pragma unroll
        for (int u = 0; u < 4; ++u) {
            if (u < mm) {
                int c = s_c[t + u];
                if (c != cprev) {
                    atomicAdd(&xp[(long)cprev * H_F + j], acc);
                    acc = 0.f;
                    cprev = c;
                }
                acc += s_g[t + u] * v[u];
            }
        }
    }
    atomicAdd(&xp[(long)cprev * H_F + j], acc);
}

__global__ __launch_bounds__(256) void pool_div(float* xp, const int* __restrict__ ccnt) {
    int i = blockIdx.x, j = threadIdx.x;
    float c = fmaxf((float)ccnt[i], 1.0f);
    xp[(long)i * H_F + j] /= c;
}

// ---------------- bit-packed pooled adjacency ----------------
__global__ __launch_bounds__(256) void build_Abits(const int* __restrict__ src,
                                                   const int* __restrict__ dst,
                                                   const int* __restrict__ cid,
                                                   unsigned* Abits) {
    int e = blockIdx.x * blockDim.x + threadIdx.x;
    if (e >= E_EDGES) return;
    int cu = cid[src[e]], cv = cid[dst[e]];
    if (cu != cv) atomicOr(&Abits[(long)cv * KW + (cu >> 5)], 1u << (cu & 31));
}

__global__ __launch_bounds__(256) void pop_di(const unsigned* __restrict__ Abits, float* di) {
    int i = blockIdx.x * blockDim.x + threadIdx.x;
    if (i >= K_CL) return;
    int c = 0;
    for (int w = 0; w < KW; ++w) c += __popc(Abits[(long)i * KW + w]);
    di[i] = rsqrtf((float)c + 1.0f);
}

// xp2[cv] = di[cv]*( sum_{A[cv][cu]=1} di[cu]*xpW2[cu] + di[cv]*xpW2[cv] ) + b2
__global__ __launch_bounds__(256) void spmm_Z(const unsigned* __restrict__ Abits,
                                              const float* __restrict__ xpW2,
                                              const float* __restrict__ di,
                                              const float* __restrict__ b2, float* xp2) {
    __shared__ unsigned s_row[KW];
    __shared__ float s_part[3][256];
    int cv = blockIdx.x;
    int tid = threadIdx.x;
    int w = tid >> 6, l = tid & 63;
    if (tid < KW) s_row[tid] = Abits[(long)cv * KW + tid];
    __syncthreads();
    float4 acc = {0.f, 0.f, 0.f, 0.f};
    const float4* Y4 = (const float4*)xpW2;
    for (int wi = w * (KW / 4); wi < (w + 1) * (KW / 4); ++wi) {
        unsigned word = s_row[wi];
        while (word) {
            int b = __ffs(word) - 1;
            word &= word - 1;
            int cu = wi * 32 + b;
            float dcu = di[cu];
            float4 y = Y4[(long)cu * 64 + l];
            acc.x += dcu * y.x; acc.y += dcu * y.y;
            acc.z += dcu * y.z; acc.w += dcu * y.w;
        }
    }
    if (w > 0) *(float4*)&s_part[w - 1][l * 4] = acc;
    __syncthreads();
    if (w == 0) {
        #pragma unroll
        for (int ww = 0; ww < 3; ++ww) {
            float4 p = *(float4*)&s_part[ww][l * 4];
            acc.x += p.x; acc.y += p.y; acc.z += p.z; acc.w += p.w;
        }
        float dv = di[cv];
        float4 ys = Y4[(long)cv * 64 + l];
        float4 o;
        o.x = dv * (acc.x + dv * ys.x) + b2[l * 4 + 0];
        o.y = dv * (acc.y + dv * ys.y) + b2[l * 4 + 1];
        o.z = dv * (acc.z + dv * ys.z) + b2[l * 4 + 2];
        o.w = dv * (acc.w + dv * ys.w) + b2[l * 4 + 3];
        *(float4*)&xp2[(long)cv * H_F + l * 4] = o;
    }
}

// ---------------- host launch ----------------
static inline size_t align256(size_t x) { return (x + 255) & ~(size_t)255; }

extern "C" void kernel_launch(void* const* d_in, const int* in_sizes, int n_in,
                              void* d_out, int out_size, void* d_ws, size_t ws_size,
                              hipStream_t stream) {
    const float* x      = (const float*)d_in[0];
    const int*   eidx   = (const int*)d_in[1];
    const float* W1     = (const float*)d_in[2];
    const float* b1     = (const float*)d_in[3];
    const float* W2     = (const float*)d_in[4];
    const float* b2     = (const float*)d_in[5];
    const float* wscore = (const float*)d_in[6];
    const float* Wskip  = (const float*)d_in[7];
    const float* bskip  = (const float*)d_in[8];
    float* out = (float*)d_out;

    const int* src = eidx;
    const int* dst = eidx + E_EDGES;

    char* ws = (char*)d_ws;
    size_t off = 0;
    auto alloc = [&](size_t bytes) { char* p = ws + off; off += align256(bytes); return p; };

    float* h     = (float*)alloc((size_t)N_NODES * H_F * 4);
    float* x1    = (float*)alloc((size_t)N_NODES * H_F * 4);
    float* raw   = (float*)alloc((size_t)N_NODES * 4);
    float* dinv  = (float*)alloc((size_t)N_NODES * 4);
    int*   cntD  = (int*)alloc((size_t)N_NODES * 4);
    int*   degS  = (int*)alloc((size_t)N_NODES * 4);
    int*   keep  = (int*)alloc((size_t)N_NODES * 4);
    int*   cid   = (int*)alloc((size_t)N_NODES * 4);
    unsigned long long* best_enc = (unsigned long long*)alloc((size_t)N_NODES * 8);
    int*   rowptr= (int*)alloc((size_t)(N_NODES + 1) * 4);
    int*   cur   = (int*)alloc((size_t)N_NODES * 4);
    int*   csr   = (int*)alloc((size_t)E_EDGES * 4);
    int*   ccnt  = (int*)alloc((size_t)K_CL * 4);
    int*   cstart= (int*)alloc((size_t)(K_CL + 1) * 4);
    int*   ccur  = (int*)alloc((size_t)K_CL * 4);
    int*   clist = (int*)alloc((size_t)N_NODES * 4);
    char*  small = alloc(64);
    unsigned* selT = (unsigned*)(small + 0);
    int* needEq    = (int*)(small + 4);
    unsigned long long* bestpack = (unsigned long long*)(small + 8);
    int* bgnode    = (int*)(small + 16);
    float* xp    = (float*)alloc((size_t)K_CL * H_F * 4);
    unsigned* Abits = (unsigned*)alloc((size_t)K_CL * KW * 4);
    float* di    = (float*)alloc((size_t)K_CL * 4);
    float* xpW2  = (float*)alloc((size_t)K_CL * H_F * 4);
    float* xp2   = (float*)alloc((size_t)K_CL * H_F * 4);
    (void)ws_size; (void)n_in; (void)in_sizes; (void)out_size;

    int nb = (N_NODES + 255) / 256;
    int eb = (E_EDGES + 255) / 256;

    // degrees
    init_nodes<<<nb, 256, 0, stream>>>(cntD, degS, best_enc, bestpack, bgnode);
    deg_edges<<<eb, 256, 0, stream>>>(src, dst, cntD, degS);
    make_dinv<<<nb, 256, 0, stream>>>(cntD, dinv);

    // h = x @ W1
    {
        dim3 grid(H_F / GBN, (N_NODES + GBM - 1) / GBM);
        gemm_db<<<grid, 256, 0, stream>>>(x, W1, h, N_NODES, H_F, IN_F,
                                          nullptr, nullptr, nullptr);
    }

    // CSR by dst + fused aggregation
    scan_generic<<<1, 1024, 0, stream>>>(cntD, rowptr, cur, N_NODES);
    csr_scatter<<<eb, 256, 0, stream>>>(src, dst, cur, csr);
    agg_fused<<<N_NODES, 256, 0, stream>>>(h, dinv, rowptr, csr, b1, wscore, x1, raw);

    // top-K
    topk_select<<<1, 1024, 0, stream>>>(raw, selT, needEq);
    topk_compact<<<1, 1024, 0, stream>>>(raw, selT, needEq, keep, cid);

    // fallback cluster
    bg_pack<<<nb, 256, 0, stream>>>(keep, degS, raw, bestpack);
    bg_node<<<nb, 256, 0, stream>>>(keep, degS, raw, bestpack, bgnode);

    // neighbor attachment
    neigh_edges<<<(2 * E_EDGES + 255) / 256, 256, 0, stream>>>(src, dst, keep, degS, best_enc);
    resolve_cid<<<nb, 256, 0, stream>>>(keep, best_enc, bgnode, cid);

    // LDS-aggregated counting sort by cluster, then chunked segmented pooling
    hipMemsetAsync(ccnt, 0, (size_t)K_CL * 4, stream);
    {
        int cb = (N_NODES + NPB - 1) / NPB;
        ccount2<<<cb, 256, 0, stream>>>(cid, ccnt);
        scan_generic<<<1, 1024, 0, stream>>>(ccnt, cstart, ccur, K_CL);
        cscatter2<<<cb, 256, 0, stream>>>(cid, ccur, clist);
    }
    hipMemsetAsync(xp, 0, (size_t)K_CL * H_F * 4, stream);
    pool_chunk<<<(N_NODES + PCH - 1) / PCH, 256, 0, stream>>>(x1, raw, clist, cid, xp);
    pool_div<<<K_CL, 256, 0, stream>>>(xp, ccnt);

    // xpW2 = xp @ W2
    {
        dim3 grid(H_F / GBN, K_CL / GBM);
        gemm_db<<<grid, 256, 0, stream>>>(xp, W2, xpW2, K_CL, H_F, H_F,
                                          nullptr, nullptr, nullptr);
    }

    // bit-packed pooled adjacency + normalized SpMM (di folded in)
    hipMemsetAsync(Abits, 0, (size_t)K_CL * KW * 4, stream);
    build_Abits<<<eb, 256, 0, stream>>>(src, dst, cid, Abits);
    pop_di<<<(K_CL + 255) / 256, 256, 0, stream>>>(Abits, di);
    spmm_Z<<<K_CL, 256, 0, stream>>>(Abits, xpW2, di, b2, xp2);

    // skip GEMM with fused broadcast epilogue: out = x1@Wskip + xp2[cid] + b_skip
    {
        dim3 grid(OUT_F / GBN, (N_NODES + GBM - 1) / GBM);
        gemm_db<<<grid, 256, 0, stream>>>(x1, Wskip, out, N_NODES, OUT_F, H_F,
                                          cid, xp2, bskip);
    }
}